// Round 5
// baseline (1562.214 us; speedup 1.0000x reference)
//
#include <hip/hip_runtime.h>
#include <hip/hip_bf16.h>

#define BT   512          // B*T = 8*64
#define DF   16           // feature dim
#define ROWF (BT * DF)    // floats per entry/node tile = 8192

// ---------- tiny index-plumbing kernels ----------

__global__ __launch_bounds__(64)
void zero_cnt_kernel(int* __restrict__ cnt, int n) {
    int i = blockIdx.x * 64 + threadIdx.x;
    if (i < n) cnt[i] = 0;
}

__global__ __launch_bounds__(256)
void count_kernel(const int* __restrict__ cn3, int* __restrict__ cnt, int E) {
    int i = blockIdx.x * blockDim.x + threadIdx.x;
    if (i < E) atomicAdd(&cnt[cn3[i]], 1);
}

// single wave: exclusive prefix sum of cnt[0..n) -> off[0..n], copy to woff
__global__ __launch_bounds__(64)
void scan_kernel(const int* __restrict__ cnt, int* __restrict__ off,
                 int* __restrict__ woff, int n)
{
    const int lane = threadIdx.x;
    int vals[32];
    int run = 0;
    #pragma unroll
    for (int j = 0; j < 32; ++j) {
        int idx = lane * 32 + j;
        int v = (idx < n) ? cnt[idx] : 0;
        vals[j] = run;
        run += v;
    }
    int incl = run;
    for (int d = 1; d < 64; d <<= 1) {
        int t = __shfl_up(incl, d, 64);
        if (lane >= d) incl += t;
    }
    int base = incl - run;
    #pragma unroll
    for (int j = 0; j < 32; ++j) {
        int idx = lane * 32 + j;
        if (idx < n) { int o = base + vals[j]; off[idx] = o; woff[idx] = o; }
    }
    if (lane == 63) off[n] = incl;
}

__global__ __launch_bounds__(256)
void scatter_kernel(const int* __restrict__ cn3, int* __restrict__ woff,
                    int* __restrict__ list, int E)
{
    int i = blockIdx.x * blockDim.x + threadIdx.x;
    if (i < E) {
        int pos = atomicAdd(&woff[cn3[i]], 1);
        list[pos] = i;
    }
}

// gather A[:, pn[e], cn[e]] into contiguous per-entry 16-float vectors
__global__ __launch_bounds__(256)
void scales_kernel(const float* __restrict__ A,
                   const int* __restrict__ pn1, const int* __restrict__ cn1,
                   const int* __restrict__ pn2, const int* __restrict__ cn2,
                   const int* __restrict__ pn3, const int* __restrict__ cn3,
                   float* __restrict__ sc1, float* __restrict__ sc2,
                   float* __restrict__ sc3,
                   int E1, int E2, int E3, int n_nodes)
{
    int i = blockIdx.x * blockDim.x + threadIdx.x;
    int total = (E1 + E2 + E3) * 16;
    if (i >= total) return;
    int e = i >> 4, f = i & 15;
    const size_t NN2 = (size_t)n_nodes * n_nodes;
    int pn, cn; float* dst;
    if (e < E1)           { pn = pn1[e];          cn = cn1[e];          dst = sc1 + (size_t)e * 16 + f; }
    else if (e < E1 + E2) { int q = e - E1;       pn = pn2[q]; cn = cn2[q]; dst = sc2 + (size_t)q * 16 + f; }
    else                  { int q = e - E1 - E2;  pn = pn3[q]; cn = cn3[q]; dst = sc3 + (size_t)q * 16 + f; }
    *dst = A[(size_t)f * NN2 + (size_t)pn * n_nodes + cn];
}

// ---------- fully fused: 3 levels + segment-mean, pure gather ----------
// grid = n_nodes*2 blocks, 256 threads. Block (node, half) walks its leaf list;
// for each leaf entry it recomputes the whole chain from x (all L3-resident):
//   h1 = fc(x[root[pe1[e1]]])*sc1[e1] + x[cn1[e1]]
//   h2 = fc(h1)*sc2[e2] + x[cn2[e2]]
//   acc += fc(h2)*sc3[e3]
// out[node] = acc/c + x[node]   (c>0; else out = x[node])
__global__ __launch_bounds__(256)
void fullfuse_kernel(const float* __restrict__ x,
                     const float* __restrict__ W,
                     const float* __restrict__ b,
                     const int* __restrict__ root,
                     const int* __restrict__ pe1,
                     const int* __restrict__ cn1,
                     const int* __restrict__ pe2,
                     const int* __restrict__ cn2,
                     const int* __restrict__ pe3,
                     const float* __restrict__ sc1,
                     const float* __restrict__ sc2,
                     const float* __restrict__ sc3,
                     const int* __restrict__ off,
                     const int* __restrict__ list,
                     float* __restrict__ out)
{
    __shared__ float sW[256];
    __shared__ float sB[16];

    const int node = blockIdx.x >> 1;
    const int half = blockIdx.x & 1;
    const int tid  = threadIdx.x;

    sW[tid] = W[tid];
    if (tid < 16) sB[tid] = b[tid];
    __syncthreads();

    const int row = half * 256 + tid;
    const int k0 = off[node], k1 = off[node + 1];

    float acc[16];
    #pragma unroll
    for (int f = 0; f < 16; ++f) acc[f] = 0.f;

    for (int k = k0; k < k1; ++k) {
        const int e3 = list[k];
        const int e2 = pe3[e3];
        const int e1 = pe2[e2];
        const int rn = root[pe1[e1]];
        const int c1 = cn1[e1];
        const int c2 = cn2[e2];

        // ---- level 1: h = fc(x[rn]) * sc1[e1] + x[c1] ----
        const float4* xr4 = (const float4*)(x + ((size_t)rn * BT + row) * DF);
        float4 a0 = xr4[0], a1 = xr4[1], a2 = xr4[2], a3 = xr4[3];
        float hin[16] = { a0.x,a0.y,a0.z,a0.w, a1.x,a1.y,a1.z,a1.w,
                          a2.x,a2.y,a2.z,a2.w, a3.x,a3.y,a3.z,a3.w };

        const float4* s1_4 = (const float4*)(sc1 + (size_t)e1 * 16);
        float4 s10 = s1_4[0], s11 = s1_4[1], s12 = s1_4[2], s13 = s1_4[3];
        float s1[16] = { s10.x,s10.y,s10.z,s10.w, s11.x,s11.y,s11.z,s11.w,
                         s12.x,s12.y,s12.z,s12.w, s13.x,s13.y,s13.z,s13.w };

        const float4* xc1_4 = (const float4*)(x + ((size_t)c1 * BT + row) * DF);
        float4 p0 = xc1_4[0], p1 = xc1_4[1], p2 = xc1_4[2], p3 = xc1_4[3];
        float xc1v[16] = { p0.x,p0.y,p0.z,p0.w, p1.x,p1.y,p1.z,p1.w,
                           p2.x,p2.y,p2.z,p2.w, p3.x,p3.y,p3.z,p3.w };

        float h[16];
        #pragma unroll
        for (int f = 0; f < 16; ++f) {
            float t = sB[f];
            #pragma unroll
            for (int d = 0; d < 16; ++d) t += hin[d] * sW[f * 16 + d];
            h[f] = t * s1[f] + xc1v[f];
        }

        // ---- level 2: h = fc(h) * sc2[e2] + x[c2] ----
        const float4* s2_4 = (const float4*)(sc2 + (size_t)e2 * 16);
        float4 s20 = s2_4[0], s21 = s2_4[1], s22 = s2_4[2], s23 = s2_4[3];
        float s2[16] = { s20.x,s20.y,s20.z,s20.w, s21.x,s21.y,s21.z,s21.w,
                         s22.x,s22.y,s22.z,s22.w, s23.x,s23.y,s23.z,s23.w };

        const float4* xc2_4 = (const float4*)(x + ((size_t)c2 * BT + row) * DF);
        float4 q0 = xc2_4[0], q1 = xc2_4[1], q2 = xc2_4[2], q3 = xc2_4[3];
        float xc2v[16] = { q0.x,q0.y,q0.z,q0.w, q1.x,q1.y,q1.z,q1.w,
                           q2.x,q2.y,q2.z,q2.w, q3.x,q3.y,q3.z,q3.w };

        float h2[16];
        #pragma unroll
        for (int f = 0; f < 16; ++f) {
            float t = sB[f];
            #pragma unroll
            for (int d = 0; d < 16; ++d) t += h[d] * sW[f * 16 + d];
            h2[f] = t * s2[f] + xc2v[f];
        }

        // ---- level 3: acc += fc(h2) * sc3[e3] ----
        const float4* s3_4 = (const float4*)(sc3 + (size_t)e3 * 16);
        float4 s30 = s3_4[0], s31 = s3_4[1], s32 = s3_4[2], s33 = s3_4[3];
        float s3[16] = { s30.x,s30.y,s30.z,s30.w, s31.x,s31.y,s31.z,s31.w,
                         s32.x,s32.y,s32.z,s32.w, s33.x,s33.y,s33.z,s33.w };

        #pragma unroll
        for (int f = 0; f < 16; ++f) {
            float t = sB[f];
            #pragma unroll
            for (int d = 0; d < 16; ++d) t += h2[d] * sW[f * 16 + d];
            acc[f] += t * s3[f];
        }
    }

    const int c = k1 - k0;
    const float inv = (c > 0) ? (1.f / (float)c) : 0.f;

    const float4* xn4 = (const float4*)(x + ((size_t)node * BT + row) * DF);
    float4 x0 = xn4[0], x1 = xn4[1], x2 = xn4[2], x3 = xn4[3];

    float4 o0 = make_float4(acc[0]*inv + x0.x,  acc[1]*inv + x0.y,
                            acc[2]*inv + x0.z,  acc[3]*inv + x0.w);
    float4 o1 = make_float4(acc[4]*inv + x1.x,  acc[5]*inv + x1.y,
                            acc[6]*inv + x1.z,  acc[7]*inv + x1.w);
    float4 o2 = make_float4(acc[8]*inv + x2.x,  acc[9]*inv + x2.y,
                            acc[10]*inv + x2.z, acc[11]*inv + x2.w);
    float4 o3 = make_float4(acc[12]*inv + x3.x, acc[13]*inv + x3.y,
                            acc[14]*inv + x3.z, acc[15]*inv + x3.w);

    float4* dst = (float4*)(out + ((size_t)node * BT + row) * DF);
    dst[0] = o0; dst[1] = o1; dst[2] = o2; dst[3] = o3;
}

// ---------- launch ----------
extern "C" void kernel_launch(void* const* d_in, const int* in_sizes, int n_in,
                              void* d_out, int out_size, void* d_ws, size_t ws_size,
                              hipStream_t stream)
{
    const float* x  = (const float*)d_in[0];
    const float* A  = (const float*)d_in[1];
    const float* W  = (const float*)d_in[2];
    const float* b  = (const float*)d_in[3];
    const int* root = (const int*)d_in[4];
    const int* pe1  = (const int*)d_in[5];
    const int* pn1  = (const int*)d_in[6];
    const int* cn1  = (const int*)d_in[7];
    const int* pe2  = (const int*)d_in[8];
    const int* pn2  = (const int*)d_in[9];
    const int* cn2  = (const int*)d_in[10];
    const int* pe3  = (const int*)d_in[11];
    const int* pn3  = (const int*)d_in[12];
    const int* cn3  = (const int*)d_in[13];

    const int E1 = in_sizes[5];
    const int E2 = in_sizes[8];
    const int E3 = in_sizes[11];
    const int n_nodes = out_size / ROWF;   // 2000

    float* out = (float*)d_out;

    // workspace layout (all small now)
    float* sc1  = (float*)d_ws;                         // E1*16
    float* sc2  = sc1 + (size_t)E1 * 16;                // E2*16
    float* sc3  = sc2 + (size_t)E2 * 16;                // E3*16
    int*   cnt  = (int*)(sc3 + (size_t)E3 * 16);        // n_nodes
    int*   off  = cnt + n_nodes;                        // n_nodes+1
    int*   woff = off + n_nodes + 1;                    // n_nodes
    int*   list = woff + n_nodes;                       // E3

    // ---- per-node leaf lists + contiguous scale vectors (tiny) ----
    zero_cnt_kernel<<<(n_nodes + 63) / 64, 64, 0, stream>>>(cnt, n_nodes);
    count_kernel<<<(E3 + 255) / 256, 256, 0, stream>>>(cn3, cnt, E3);
    scan_kernel<<<1, 64, 0, stream>>>(cnt, off, woff, n_nodes);
    scatter_kernel<<<(E3 + 255) / 256, 256, 0, stream>>>(cn3, woff, list, E3);
    {
        int total = (E1 + E2 + E3) * 16;
        scales_kernel<<<(total + 255) / 256, 256, 0, stream>>>(
            A, pn1, cn1, pn2, cn2, pn3, cn3, sc1, sc2, sc3, E1, E2, E3, n_nodes);
    }

    // ---- one fused kernel: 3 levels + segment mean ----
    fullfuse_kernel<<<n_nodes * 2, 256, 0, stream>>>(
        x, W, b, root, pe1, cn1, pe2, cn2, pe3,
        sc1, sc2, sc3, off, list, out);
}